// Round 18
// baseline (150.632 us; speedup 1.0000x reference)
//
#include <hip/hip_runtime.h>
#include <math.h>

#define N_REL  8
#define IN_CH  16
#define HID_CH 32
#define OUT_CH 2

#define BIN_BITS  9
#define BIN_NODES 512                    // nodes per coarse bin
#define KPB       (BIN_NODES * N_REL)    // 4096 (node,rel) keys per bin
#define NCHUNK    256                    // partition chunks
#define XW_TILE   64

// float -> bf16 round-to-nearest-even
static __device__ __forceinline__ unsigned short f2b(float f) {
    unsigned int u = __float_as_uint(f);
    u = (u + 0x7FFFu + ((u >> 16) & 1u)) >> 16;
    return (unsigned short)u;
}
static __device__ __forceinline__ float b2f(unsigned short s) {
    return __uint_as_float(((unsigned int)s) << 16);
}

// ---------------------------------------------------------------------------
// prep: blocks [0,nxw) compute xW16 = bf16(x @ W1); blocks [nxw,nxw+NCHUNK)
// do the per-chunk bin histogram (independent work overlapped).
// ---------------------------------------------------------------------------
__global__ __launch_bounds__(256) void prep_kernel(const float* __restrict__ x,
                                                   const float* __restrict__ W1,
                                                   unsigned short* __restrict__ xW16,
                                                   const int* __restrict__ dst,
                                                   int* __restrict__ H,
                                                   int N, int E, int nbins,
                                                   int chunksz, int nxw) {
    __shared__ float sx[XW_TILE * IN_CH];   // 4 KB (xw branch)
    __shared__ int hist[256];               // 1 KB (hist branch)
    int t = threadIdx.x;

    if ((int)blockIdx.x < nxw) {
        int node0 = blockIdx.x * XW_TILE;
        {
            int i4 = node0 * 4 + t;
            float4 v = make_float4(0.f, 0.f, 0.f, 0.f);
            if (i4 < N * 4) v = ((const float4*)x)[i4];
            ((float4*)sx)[t] = v;
        }
        __syncthreads();

        int r = t >> 5, c = t & 31;
        float w[IN_CH];
#pragma unroll
        for (int f = 0; f < IN_CH; ++f)
            w[f] = W1[(r * IN_CH + f) * HID_CH + c];

        int lim = N - node0; if (lim > XW_TILE) lim = XW_TILE;
        for (int ni = 0; ni < lim; ++ni) {
            const float4* xs = (const float4*)(sx + ni * IN_CH);
            float4 v0 = xs[0], v1 = xs[1], v2 = xs[2], v3 = xs[3];
            float a;
            a  = v0.x * w[0]  + v0.y * w[1]  + v0.z * w[2]  + v0.w * w[3];
            a += v1.x * w[4]  + v1.y * w[5]  + v1.z * w[6]  + v1.w * w[7];
            a += v2.x * w[8]  + v2.y * w[9]  + v2.z * w[10] + v2.w * w[11];
            a += v3.x * w[12] + v3.y * w[13] + v3.z * w[14] + v3.w * w[15];
            xW16[(node0 + ni) * (N_REL * HID_CH) + t] = f2b(a);
        }
    } else {
        int chunk = blockIdx.x - nxw;
        int e0 = chunk * chunksz;
        int e1 = e0 + chunksz; if (e1 > E) e1 = E;

        for (int i = t; i < nbins; i += 256) hist[i] = 0;
        __syncthreads();
        for (int e = e0 + t; e < e1; e += 256)
            atomicAdd(&hist[dst[e] >> BIN_BITS], 1);
        __syncthreads();
        for (int i = t; i < nbins; i += 256)
            H[i * NCHUNK + chunk] = hist[i];
    }
}

// ---------------------------------------------------------------------------
// part_scatter (self-scanning): each block computes its per-bin base offsets
// from raw H; chunk-0 block publishes binstart[]. No separate scan kernels.
// pack: (localdst<<20) | (rel<<17) | src
// ---------------------------------------------------------------------------
__global__ __launch_bounds__(256) void part_scatter_kernel(const int* __restrict__ src,
                                                           const int* __restrict__ dst,
                                                           const int* __restrict__ rel,
                                                           const int* __restrict__ H,
                                                           int* __restrict__ binstart,
                                                           int* __restrict__ be,
                                                           int E, int nbins, int chunksz) {
    __shared__ int base[256];
    __shared__ int scanbuf[256];
    __shared__ int fil[256];
    int chunk = blockIdx.x;
    int i = threadIdx.x;
    int e0 = chunk * chunksz;
    int e1 = e0 + chunksz; if (e1 > E) e1 = E;

    // per-bin row prefix (up to my chunk) and row total
    int mypre = 0, mytot = 0;
    if (i < nbins) {
        const int* row = H + i * NCHUNK;
        for (int ch = 0; ch < NCHUNK; ++ch) {
            int v = row[ch];
            mytot += v;
            if (ch < chunk) mypre += v;
        }
    }
    scanbuf[i] = mytot;
    __syncthreads();
#pragma unroll
    for (int d = 1; d < 256; d <<= 1) {
        int add = (i >= d) ? scanbuf[i - d] : 0;
        __syncthreads();
        scanbuf[i] += add;
        __syncthreads();
    }
    int excl = scanbuf[i] - mytot;           // bin start
    base[i] = excl + mypre;                  // this (bin,chunk) run start
    fil[i]  = 0;
    if (chunk == 0 && i <= nbins) binstart[i] = excl;   // i==nbins -> E
    __syncthreads();

    for (int e = e0 + i; e < e1; e += 256) {
        int d = dst[e];
        int b = d >> BIN_BITS;
        int slot = base[b] + atomicAdd(&fil[b], 1);
        be[slot] = ((d & (BIN_NODES - 1)) << 20) | (rel[e] << 17) | src[e];
    }
}

// ---------------------------------------------------------------------------
// bin_build: one block per bin — LDS counting sort -> rowptr[], csr[], einv[].
// csr entry = (src<<3)|rel (== hW16 gather index); einv = 1/seglen;
// rowptr[n+1] = end of node n's edge range.
// ---------------------------------------------------------------------------
__global__ __launch_bounds__(256) void bin_build_kernel(const int* __restrict__ be,
                                                        const int* __restrict__ binstart,
                                                        int* __restrict__ rowptr,
                                                        int* __restrict__ csr,
                                                        float* __restrict__ einv,
                                                        int E, int nbins) {
    int b  = blockIdx.x;
    int s0 = binstart[b];
    int s1 = binstart[b + 1];
    int t  = threadIdx.x;

    __shared__ int cnt[KPB];
    __shared__ int off[KPB];
    __shared__ int fil[KPB];
    __shared__ int ws[4];

    for (int i = t; i < KPB; i += 256) { cnt[i] = 0; fil[i] = 0; }
    __syncthreads();

    for (int p = s0 + t; p < s1; p += 256)
        atomicAdd(&cnt[be[p] >> 17], 1);          // key = (localdst<<3)|rel
    __syncthreads();

    int kbase = t * 16;
    int loc[16];
    int sum = 0;
#pragma unroll
    for (int i = 0; i < 16; ++i) { loc[i] = sum; sum += cnt[kbase + i]; }

    int lane = t & 63, wid = t >> 6;
    int v = sum;
#pragma unroll
    for (int o = 1; o < 64; o <<= 1) {
        int u = __shfl_up(v, o, 64);
        if (lane >= o) v += u;
    }
    if (lane == 63) ws[wid] = v;
    __syncthreads();
    int woff = 0;
    for (int i = 0; i < wid; ++i) woff += ws[i];
    int excl = woff + (v - sum);
#pragma unroll
    for (int i = 0; i < 16; ++i) off[kbase + i] = excl + loc[i];
    __syncthreads();

    // rowptr: node n's range end = end of its rel-7 segment
    for (int i = t; i < KPB; i += 256)
        if ((i & 7) == 7)
            rowptr[b * BIN_NODES + (i >> 3) + 1] = s0 + off[i] + cnt[i];
    if (b == 0 && t == 0) rowptr[0] = 0;

    for (int p = s0 + t; p < s1; p += 256) {
        int pk = be[p];
        int k  = pk >> 17;
        int slot = s0 + off[k] + atomicAdd(&fil[k], 1);
        csr[slot]  = ((pk & 0x1FFFF) << 3) | (k & 7);
        einv[slot] = 1.0f / (float)cnt[k];
    }
}

// ---------------------------------------------------------------------------
// Stage W2T+root2 as float2: sw2[f*9+j], j<8 = W2[j][f][:], j=8 = root2[f][:]
// ---------------------------------------------------------------------------
#define STAGE_SW2(sw2, W2, root2)                                              \
    for (int i = threadIdx.x; i < 288; i += 256) {                             \
        int f = i / 9, j = i - f * 9;                                          \
        float a, bb;                                                           \
        if (j < 8) { a = W2[(j * HID_CH + f) * 2]; bb = W2[(j * HID_CH + f) * 2 + 1]; } \
        else       { a = root2[f * 2];             bb = root2[f * 2 + 1]; }    \
        sw2[i] = make_float2(a, bb);                                           \
    }

// ---------------------------------------------------------------------------
// Epilogue v2 (16 steps): two 16-lane groups accumulate half the channels
// each for output jj=min(c&15,8); one shfl_xor(16) combines.
// ---------------------------------------------------------------------------
#define EPILOGUE_V2(sw2, hval, node, c, hW16, hroot, b2)                       \
    {                                                                          \
        int g  = (c >> 4) << 4;                                                \
        int jj = c & 15; if (jj > 8) jj = 8;                                   \
        float o0 = 0.0f, o1 = 0.0f;                                            \
        _Pragma("unroll")                                                      \
        for (int k = 0; k < 16; ++k) {                                         \
            float hf = __shfl(hval, g + k, 32);                                \
            float2 wv = sw2[(g + k) * 9 + jj];                                 \
            o0 = fmaf(hf, wv.x, o0);                                           \
            o1 = fmaf(hf, wv.y, o1);                                           \
        }                                                                      \
        o0 += __shfl_xor(o0, 16, 32);                                          \
        o1 += __shfl_xor(o1, 16, 32);                                          \
        if (c < 8) {                                                           \
            hW16[((node) << 3) + c] = ((unsigned)f2b(o1) << 16) | f2b(o0);     \
        } else if (c == 8) {                                                   \
            *(float2*)(hroot + ((long)(node) << 1)) =                          \
                make_float2(o0 + b2[0], o1 + b2[1]);                           \
        }                                                                      \
    }

// ---------------------------------------------------------------------------
// l1 fused (r16-proven body): HALF-WAVE per node, lane = channel c. FLAT
// 8-deep edge loop, separate csr/einv streams, 1-op gather addressing.
// ---------------------------------------------------------------------------
__global__ __launch_bounds__(256) void l1_fused_kernel(const float* __restrict__ x,
                                                       const int* __restrict__ csr,
                                                       const float* __restrict__ einv,
                                                       const int* __restrict__ rowptr,
                                                       const unsigned short* __restrict__ xW16,
                                                       const float* __restrict__ root1,
                                                       const float* __restrict__ b1,
                                                       const float* __restrict__ W2,
                                                       const float* __restrict__ root2,
                                                       const float* __restrict__ b2,
                                                       unsigned int* __restrict__ hW16,
                                                       float* __restrict__ hroot, int N) {
    __shared__ float2 sw2[32 * 9];   // 2.25 KB
    STAGE_SW2(sw2, W2, root2)
    __syncthreads();

    int gid  = blockIdx.x * 256 + threadIdx.x;
    int node = gid >> 5;
    int c    = gid & 31;
    if (node >= N) return;

    int p0 = __ldg(&rowptr[node]);
    int p1 = __ldg(&rowptr[node + 1]);

    float acc0 = 0.0f, acc1 = 0.0f;
    int p = p0;
    for (; p + 7 < p1; p += 8) {            // 8 independent edge chains
        int v0 = csr[p],     v1 = csr[p + 1], v2 = csr[p + 2], v3 = csr[p + 3];
        int v4 = csr[p + 4], v5 = csr[p + 5], v6 = csr[p + 6], v7 = csr[p + 7];
        float i0 = einv[p],     i1 = einv[p + 1], i2 = einv[p + 2], i3 = einv[p + 3];
        float i4 = einv[p + 4], i5 = einv[p + 5], i6 = einv[p + 6], i7 = einv[p + 7];
        float a0 = b2f(xW16[(v0 << 5) + c]);
        float a1 = b2f(xW16[(v1 << 5) + c]);
        float a2 = b2f(xW16[(v2 << 5) + c]);
        float a3 = b2f(xW16[(v3 << 5) + c]);
        float a4 = b2f(xW16[(v4 << 5) + c]);
        float a5 = b2f(xW16[(v5 << 5) + c]);
        float a6 = b2f(xW16[(v6 << 5) + c]);
        float a7 = b2f(xW16[(v7 << 5) + c]);
        acc0 = fmaf(a0, i0, acc0);
        acc1 = fmaf(a1, i1, acc1);
        acc0 = fmaf(a2, i2, acc0);
        acc1 = fmaf(a3, i3, acc1);
        acc0 = fmaf(a4, i4, acc0);
        acc1 = fmaf(a5, i5, acc1);
        acc0 = fmaf(a6, i6, acc0);
        acc1 = fmaf(a7, i7, acc1);
    }
    for (; p + 3 < p1; p += 4) {
        int v0 = csr[p], v1 = csr[p + 1], v2 = csr[p + 2], v3 = csr[p + 3];
        float i0 = einv[p], i1 = einv[p + 1], i2 = einv[p + 2], i3 = einv[p + 3];
        acc0 = fmaf(b2f(xW16[(v0 << 5) + c]), i0, acc0);
        acc1 = fmaf(b2f(xW16[(v1 << 5) + c]), i1, acc1);
        acc0 = fmaf(b2f(xW16[(v2 << 5) + c]), i2, acc0);
        acc1 = fmaf(b2f(xW16[(v3 << 5) + c]), i3, acc1);
    }
    if (p + 1 < p1) {
        int v0 = csr[p], v1 = csr[p + 1];
        acc0 = fmaf(b2f(xW16[(v0 << 5) + c]), einv[p], acc0);
        acc1 = fmaf(b2f(xW16[(v1 << 5) + c]), einv[p + 1], acc1);
        p += 2;
    }
    if (p < p1)
        acc0 = fmaf(b2f(xW16[(csr[p] << 5) + c]), einv[p], acc0);

    // root term + bias + relu
    const float4* xs = (const float4*)(x + ((long)node << 4));
    float4 v0 = xs[0], v1 = xs[1], v2 = xs[2], v3 = xs[3];
    const float* wr = root1 + c;
    float acc = acc0 + acc1 + b1[c];
    acc += v0.x * wr[0]   + v0.y * wr[32]  + v0.z * wr[64]  + v0.w * wr[96];
    acc += v1.x * wr[128] + v1.y * wr[160] + v1.z * wr[192] + v1.w * wr[224];
    acc += v2.x * wr[256] + v2.y * wr[288] + v2.z * wr[320] + v2.w * wr[352];
    acc += v3.x * wr[384] + v3.y * wr[416] + v3.z * wr[448] + v3.w * wr[480];
    float hval = fmaxf(acc, 0.0f);

    EPILOGUE_V2(sw2, hval, node, c, hW16, hroot, b2)
}

// ---------------------------------------------------------------------------
// l1 fallback (no room for xW16): half-wave per node, direct per-edge dot.
// ---------------------------------------------------------------------------
__global__ __launch_bounds__(256) void l1_fb_kernel(const float* __restrict__ x,
                                                    const int* __restrict__ csr,
                                                    const float* __restrict__ einv,
                                                    const int* __restrict__ rowptr,
                                                    const float* __restrict__ W1,
                                                    const float* __restrict__ root1,
                                                    const float* __restrict__ b1,
                                                    const float* __restrict__ W2,
                                                    const float* __restrict__ root2,
                                                    const float* __restrict__ b2,
                                                    unsigned int* __restrict__ hW16,
                                                    float* __restrict__ hroot, int N) {
    __shared__ float sW[N_REL * IN_CH * HID_CH];   // 16 KB
    __shared__ float2 sw2[32 * 9];
    for (int i = threadIdx.x; i < N_REL * IN_CH * HID_CH; i += 256) sW[i] = W1[i];
    STAGE_SW2(sw2, W2, root2)
    __syncthreads();

    int gid  = blockIdx.x * 256 + threadIdx.x;
    int node = gid >> 5;
    int c    = gid & 31;
    if (node >= N) return;

    int p0 = __ldg(&rowptr[node]);
    int p1 = __ldg(&rowptr[node + 1]);

    float acc = 0.0f;
    for (int p = p0; p < p1; ++p) {
        int v = csr[p];
        int s = v >> 3, r = v & 7;
        const float4* xsv = (const float4*)(x + ((long)s << 4));
        float4 q0 = xsv[0], q1 = xsv[1], q2 = xsv[2], q3 = xsv[3];
        const float* w = sW + ((r * IN_CH) * HID_CH) + c;
        float a;
        a  = q0.x * w[0]   + q0.y * w[32]  + q0.z * w[64]  + q0.w * w[96];
        a += q1.x * w[128] + q1.y * w[160] + q1.z * w[192] + q1.w * w[224];
        a += q2.x * w[256] + q2.y * w[288] + q2.z * w[320] + q2.w * w[352];
        a += q3.x * w[384] + q3.y * w[416] + q3.z * w[448] + q3.w * w[480];
        acc = fmaf(a, einv[p], acc);
    }

    const float4* xs = (const float4*)(x + ((long)node << 4));
    float4 v0 = xs[0], v1 = xs[1], v2 = xs[2], v3 = xs[3];
    const float* wr = root1 + c;
    acc += b1[c];
    acc += v0.x * wr[0]   + v0.y * wr[32]  + v0.z * wr[64]  + v0.w * wr[96];
    acc += v1.x * wr[128] + v1.y * wr[160] + v1.z * wr[192] + v1.w * wr[224];
    acc += v2.x * wr[256] + v2.y * wr[288] + v2.z * wr[320] + v2.w * wr[352];
    acc += v3.x * wr[384] + v3.y * wr[416] + v3.z * wr[448] + v3.w * wr[480];
    float hval = fmaxf(acc, 0.0f);

    EPILOGUE_V2(sw2, hval, node, c, hW16, hroot, b2)
}

// ---------------------------------------------------------------------------
// l2 flat: 16 lanes per node, flat edge loop; hW16 gather index == csr word.
// ---------------------------------------------------------------------------
__global__ __launch_bounds__(256) void l2_flat_kernel(const int* __restrict__ csr,
                                                      const float* __restrict__ einv,
                                                      const int* __restrict__ rowptr,
                                                      const unsigned int* __restrict__ hW16,
                                                      const float* __restrict__ hroot,
                                                      float* __restrict__ out, int N) {
    int gid  = blockIdx.x * 256 + threadIdx.x;
    int node = gid >> 4;
    int l    = gid & 15;
    if (node >= N) return;

    int p0 = __ldg(&rowptr[node]);
    int p1 = __ldg(&rowptr[node + 1]);

    float o0 = 0.0f, o1 = 0.0f;
    for (int p = p0 + l; p < p1; p += 16) {
        int v = csr[p];
        float w = einv[p];
        unsigned u = hW16[v];
        o0 = fmaf(b2f((unsigned short)u), w, o0);
        o1 = fmaf(b2f((unsigned short)(u >> 16)), w, o1);
    }

#pragma unroll
    for (int m = 1; m < 16; m <<= 1) {
        o0 += __shfl_xor(o0, m, 64);
        o1 += __shfl_xor(o1, m, 64);
    }

    if (l == 0) {
        float2 rt = *(const float2*)(hroot + ((long)node << 1));   // includes b2
        o0 += rt.x; o1 += rt.y;
        float mx = fmaxf(o0, o1);
        float lg = mx + logf(__expf(o0 - mx) + __expf(o1 - mx));
        *(float2*)(out + ((long)node << 1)) = make_float2(o0 - lg, o1 - lg);
    }
}

// ---------------------------------------------------------------------------
extern "C" void kernel_launch(void* const* d_in, const int* in_sizes, int n_in,
                              void* d_out, int out_size, void* d_ws, size_t ws_size,
                              hipStream_t stream) {
    const float* x     = (const float*)d_in[0];
    const int*   eidx  = (const int*)d_in[1];
    const int*   etype = (const int*)d_in[2];
    const float* W1    = (const float*)d_in[3];
    const float* root1 = (const float*)d_in[4];
    const float* b1    = (const float*)d_in[5];
    const float* W2    = (const float*)d_in[6];
    const float* root2 = (const float*)d_in[7];
    const float* b2    = (const float*)d_in[8];
    float* out = (float*)d_out;

    const int N = in_sizes[0] / IN_CH;
    const int E = in_sizes[2];
    const int nbins   = (N + BIN_NODES - 1) >> BIN_BITS;
    const int chunksz = (E + NCHUNK - 1) / NCHUNK;
    const int M2      = nbins * NCHUNK;
    const int* src = eidx;
    const int* dst = eidx + E;

    char* wp = (char*)d_ws;
    auto take = [&](size_t bytes) {
        char* p = wp;
        wp += (bytes + 63) & ~(size_t)63;
        return p;
    };
    int*   H        = (int*)take((size_t)M2 * sizeof(int));
    int*   binstart = (int*)take(512 * sizeof(int));
    int*   rowptr   = (int*)take((size_t)(nbins * BIN_NODES + 1) * sizeof(int));
    int*   csr      = (int*)take((size_t)E * sizeof(int));
    float* einv     = (float*)take((size_t)E * sizeof(float));
    int*   be       = (int*)take((size_t)E * sizeof(int));
    unsigned int* hW16 = (unsigned int*)take((size_t)N * N_REL * sizeof(unsigned int));
    float* hroot    = (float*)take((size_t)N * 2 * sizeof(float));
    unsigned short* xW16 = (unsigned short*)take((size_t)N * N_REL * HID_CH * sizeof(unsigned short));
    bool use_xw = ((size_t)(wp - (char*)d_ws) <= ws_size);

    const int B = 256;
    const int nxw = use_xw ? (N + XW_TILE - 1) / XW_TILE : 0;

    prep_kernel<<<nxw + NCHUNK, B, 0, stream>>>(x, W1, xW16, dst, H, N, E, nbins, chunksz, nxw);
    part_scatter_kernel<<<NCHUNK, B, 0, stream>>>(src, dst, etype, H, binstart, be, E, nbins, chunksz);
    bin_build_kernel<<<nbins, B, 0, stream>>>(be, binstart, rowptr, csr, einv, E, nbins);

    if (use_xw) {
        l1_fused_kernel<<<(N * 32 + B - 1) / B, B, 0, stream>>>(
            x, csr, einv, rowptr, xW16, root1, b1, W2, root2, b2, hW16, hroot, N);
    } else {
        l1_fb_kernel<<<(N * 32 + B - 1) / B, B, 0, stream>>>(
            x, csr, einv, rowptr, W1, root1, b1, W2, root2, b2, hW16, hroot, N);
    }

    l2_flat_kernel<<<(N * 16 + B - 1) / B, B, 0, stream>>>(csr, einv, rowptr, hW16, hroot, out, N);
}

// Round 19
// 150.028 us; speedup vs baseline: 1.0040x; 1.0040x over previous
//
#include <hip/hip_runtime.h>
#include <math.h>

#define N_REL  8
#define IN_CH  16
#define HID_CH 32
#define OUT_CH 2

#define BIN_BITS  9
#define BIN_NODES 512                    // nodes per coarse bin
#define KPB       (BIN_NODES * N_REL)    // 4096 (node,rel) keys per bin
#define NCHUNK    256                    // partition chunks
#define XW_TILE   64

// float -> bf16 round-to-nearest-even
static __device__ __forceinline__ unsigned short f2b(float f) {
    unsigned int u = __float_as_uint(f);
    u = (u + 0x7FFFu + ((u >> 16) & 1u)) >> 16;
    return (unsigned short)u;
}
static __device__ __forceinline__ float b2f(unsigned short s) {
    return __uint_as_float(((unsigned int)s) << 16);
}

// ---------------------------------------------------------------------------
// prep: blocks [0,nxw) compute xW16 = bf16(x @ W1); blocks [nxw,nxw+NCHUNK)
// do the per-chunk bin histogram (independent work overlapped).
// ---------------------------------------------------------------------------
__global__ __launch_bounds__(256) void prep_kernel(const float* __restrict__ x,
                                                   const float* __restrict__ W1,
                                                   unsigned short* __restrict__ xW16,
                                                   const int* __restrict__ dst,
                                                   int* __restrict__ H,
                                                   int N, int E, int nbins,
                                                   int chunksz, int nxw) {
    __shared__ float sx[XW_TILE * IN_CH];   // 4 KB (xw branch)
    __shared__ int hist[256];               // 1 KB (hist branch)
    int t = threadIdx.x;

    if ((int)blockIdx.x < nxw) {
        int node0 = blockIdx.x * XW_TILE;
        {
            int i4 = node0 * 4 + t;
            float4 v = make_float4(0.f, 0.f, 0.f, 0.f);
            if (i4 < N * 4) v = ((const float4*)x)[i4];
            ((float4*)sx)[t] = v;
        }
        __syncthreads();

        int r = t >> 5, c = t & 31;
        float w[IN_CH];
#pragma unroll
        for (int f = 0; f < IN_CH; ++f)
            w[f] = W1[(r * IN_CH + f) * HID_CH + c];

        int lim = N - node0; if (lim > XW_TILE) lim = XW_TILE;
        for (int ni = 0; ni < lim; ++ni) {
            const float4* xs = (const float4*)(sx + ni * IN_CH);
            float4 v0 = xs[0], v1 = xs[1], v2 = xs[2], v3 = xs[3];
            float a;
            a  = v0.x * w[0]  + v0.y * w[1]  + v0.z * w[2]  + v0.w * w[3];
            a += v1.x * w[4]  + v1.y * w[5]  + v1.z * w[6]  + v1.w * w[7];
            a += v2.x * w[8]  + v2.y * w[9]  + v2.z * w[10] + v2.w * w[11];
            a += v3.x * w[12] + v3.y * w[13] + v3.z * w[14] + v3.w * w[15];
            xW16[(node0 + ni) * (N_REL * HID_CH) + t] = f2b(a);
        }
    } else {
        int chunk = blockIdx.x - nxw;
        int e0 = chunk * chunksz;
        int e1 = e0 + chunksz; if (e1 > E) e1 = E;

        for (int i = t; i < nbins; i += 256) hist[i] = 0;
        __syncthreads();
        for (int e = e0 + t; e < e1; e += 256)
            atomicAdd(&hist[dst[e] >> BIN_BITS], 1);
        __syncthreads();
        for (int i = t; i < nbins; i += 256)
            H[i * NCHUNK + chunk] = hist[i];
    }
}

// ---------------------------------------------------------------------------
// part_scatter (self-scanning): each block computes its per-bin base offsets
// from raw H (int4-vectorized row walk); chunk-0 block publishes binstart[].
// pack: (localdst<<20) | (rel<<17) | src
// ---------------------------------------------------------------------------
__global__ __launch_bounds__(256) void part_scatter_kernel(const int* __restrict__ src,
                                                           const int* __restrict__ dst,
                                                           const int* __restrict__ rel,
                                                           const int* __restrict__ H,
                                                           int* __restrict__ binstart,
                                                           int* __restrict__ be,
                                                           int E, int nbins, int chunksz) {
    __shared__ int base[256];
    __shared__ int scanbuf[256];
    __shared__ int fil[256];
    int chunk = blockIdx.x;
    int i = threadIdx.x;
    int e0 = chunk * chunksz;
    int e1 = e0 + chunksz; if (e1 > E) e1 = E;

    // per-bin row prefix (up to my chunk) and row total, int4-vectorized
    int mypre = 0, mytot = 0;
    if (i < nbins) {
        const int4* row4 = (const int4*)(H + i * NCHUNK);
        for (int q = 0; q < NCHUNK / 4; ++q) {
            int4 v = row4[q];
            int b4 = q * 4;
            int s = v.x + v.y + v.z + v.w;
            mytot += s;
            if (b4 + 3 < chunk) {
                mypre += s;
            } else {
                if (b4 < chunk)     mypre += v.x;
                if (b4 + 1 < chunk) mypre += v.y;
                if (b4 + 2 < chunk) mypre += v.z;
            }
        }
    }
    scanbuf[i] = mytot;
    __syncthreads();
#pragma unroll
    for (int d = 1; d < 256; d <<= 1) {
        int add = (i >= d) ? scanbuf[i - d] : 0;
        __syncthreads();
        scanbuf[i] += add;
        __syncthreads();
    }
    int excl = scanbuf[i] - mytot;           // bin start
    base[i] = excl + mypre;                  // this (bin,chunk) run start
    fil[i]  = 0;
    if (chunk == 0 && i <= nbins) binstart[i] = excl;   // i==nbins -> E
    __syncthreads();

    for (int e = e0 + i; e < e1; e += 256) {
        int d = dst[e];
        int b = d >> BIN_BITS;
        int slot = base[b] + atomicAdd(&fil[b], 1);
        be[slot] = ((d & (BIN_NODES - 1)) << 20) | (rel[e] << 17) | src[e];
    }
}

// ---------------------------------------------------------------------------
// bin_build: one block per bin — LDS counting sort -> rowptr[], csr[], einv[].
// LDS slimmed to cnt[]+fil[] (32 KB): after the scan, fil[k] holds the
// ABSOLUTE segment start, and the scatter's atomicAdd returns the final slot.
// csr entry = (src<<3)|rel (== hW16 gather index); einv = 1/seglen.
// ---------------------------------------------------------------------------
__global__ __launch_bounds__(256) void bin_build_kernel(const int* __restrict__ be,
                                                        const int* __restrict__ binstart,
                                                        int* __restrict__ rowptr,
                                                        int* __restrict__ csr,
                                                        float* __restrict__ einv,
                                                        int E, int nbins) {
    int b  = blockIdx.x;
    int s0 = binstart[b];
    int s1 = binstart[b + 1];
    int t  = threadIdx.x;

    __shared__ int cnt[KPB];   // 16 KB
    __shared__ int fil[KPB];   // 16 KB (absolute starts after scan)
    __shared__ int ws[4];

    for (int i = t; i < KPB; i += 256) cnt[i] = 0;
    __syncthreads();

    for (int p = s0 + t; p < s1; p += 256)
        atomicAdd(&cnt[be[p] >> 17], 1);          // key = (localdst<<3)|rel
    __syncthreads();

    int kbase = t * 16;
    int loc[16];
    int sum = 0;
#pragma unroll
    for (int i = 0; i < 16; ++i) { loc[i] = sum; sum += cnt[kbase + i]; }

    int lane = t & 63, wid = t >> 6;
    int v = sum;
#pragma unroll
    for (int o = 1; o < 64; o <<= 1) {
        int u = __shfl_up(v, o, 64);
        if (lane >= o) v += u;
    }
    if (lane == 63) ws[wid] = v;
    __syncthreads();
    int woff = 0;
    for (int i = 0; i < wid; ++i) woff += ws[i];
    int excl = woff + (v - sum);

    // publish absolute starts + rowptr (node end = rel-7 segment end)
#pragma unroll
    for (int i = 0; i < 16; ++i) {
        int key = kbase + i;
        int absstart = s0 + excl + loc[i];
        fil[key] = absstart;
        if ((key & 7) == 7)
            rowptr[b * BIN_NODES + (key >> 3) + 1] = absstart + cnt[key];
    }
    if (b == 0 && t == 0) rowptr[0] = 0;
    __syncthreads();

    for (int p = s0 + t; p < s1; p += 256) {
        int pk = be[p];
        int k  = pk >> 17;
        int slot = atomicAdd(&fil[k], 1);
        csr[slot]  = ((pk & 0x1FFFF) << 3) | (k & 7);
        einv[slot] = 1.0f / (float)cnt[k];
    }
}

// ---------------------------------------------------------------------------
// Stage W2T+root2 as float2: sw2[f*9+j], j<8 = W2[j][f][:], j=8 = root2[f][:]
// ---------------------------------------------------------------------------
#define STAGE_SW2(sw2, W2, root2)                                              \
    for (int i = threadIdx.x; i < 288; i += 256) {                             \
        int f = i / 9, j = i - f * 9;                                          \
        float a, bb;                                                           \
        if (j < 8) { a = W2[(j * HID_CH + f) * 2]; bb = W2[(j * HID_CH + f) * 2 + 1]; } \
        else       { a = root2[f * 2];             bb = root2[f * 2 + 1]; }    \
        sw2[i] = make_float2(a, bb);                                           \
    }

// ---------------------------------------------------------------------------
// Epilogue v2 (16 steps): two 16-lane groups accumulate half the channels
// each for output jj=min(c&15,8); one shfl_xor(16) combines.
// ---------------------------------------------------------------------------
#define EPILOGUE_V2(sw2, hval, node, c, hW16, hroot, b2)                       \
    {                                                                          \
        int g  = (c >> 4) << 4;                                                \
        int jj = c & 15; if (jj > 8) jj = 8;                                   \
        float o0 = 0.0f, o1 = 0.0f;                                            \
        _Pragma("unroll")                                                      \
        for (int k = 0; k < 16; ++k) {                                         \
            float hf = __shfl(hval, g + k, 32);                                \
            float2 wv = sw2[(g + k) * 9 + jj];                                 \
            o0 = fmaf(hf, wv.x, o0);                                           \
            o1 = fmaf(hf, wv.y, o1);                                           \
        }                                                                      \
        o0 += __shfl_xor(o0, 16, 32);                                          \
        o1 += __shfl_xor(o1, 16, 32);                                          \
        if (c < 8) {                                                           \
            hW16[((node) << 3) + c] = ((unsigned)f2b(o1) << 16) | f2b(o0);     \
        } else if (c == 8) {                                                   \
            *(float2*)(hroot + ((long)(node) << 1)) =                          \
                make_float2(o0 + b2[0], o1 + b2[1]);                           \
        }                                                                      \
    }

// ---------------------------------------------------------------------------
// l1 fused: HALF-WAVE per node, lane = channel c. FLAT 8-deep edge loop,
// separate csr/einv streams, 1-op gather addressing. Root-term x loads
// hoisted above the loop to overlap the first gather batch.
// ---------------------------------------------------------------------------
__global__ __launch_bounds__(256) void l1_fused_kernel(const float* __restrict__ x,
                                                       const int* __restrict__ csr,
                                                       const float* __restrict__ einv,
                                                       const int* __restrict__ rowptr,
                                                       const unsigned short* __restrict__ xW16,
                                                       const float* __restrict__ root1,
                                                       const float* __restrict__ b1,
                                                       const float* __restrict__ W2,
                                                       const float* __restrict__ root2,
                                                       const float* __restrict__ b2,
                                                       unsigned int* __restrict__ hW16,
                                                       float* __restrict__ hroot, int N) {
    __shared__ float2 sw2[32 * 9];   // 2.25 KB
    STAGE_SW2(sw2, W2, root2)
    __syncthreads();

    int gid  = blockIdx.x * 256 + threadIdx.x;
    int node = gid >> 5;
    int c    = gid & 31;
    if (node >= N) return;

    int p0 = __ldg(&rowptr[node]);
    int p1 = __ldg(&rowptr[node + 1]);

    // hoisted independent loads (overlap first gather batch)
    const float4* xs = (const float4*)(x + ((long)node << 4));
    float4 xv0 = xs[0], xv1 = xs[1], xv2 = xs[2], xv3 = xs[3];

    float acc0 = 0.0f, acc1 = 0.0f;
    int p = p0;
    for (; p + 7 < p1; p += 8) {            // 8 independent edge chains
        int v0 = csr[p],     v1 = csr[p + 1], v2 = csr[p + 2], v3 = csr[p + 3];
        int v4 = csr[p + 4], v5 = csr[p + 5], v6 = csr[p + 6], v7 = csr[p + 7];
        float i0 = einv[p],     i1 = einv[p + 1], i2 = einv[p + 2], i3 = einv[p + 3];
        float i4 = einv[p + 4], i5 = einv[p + 5], i6 = einv[p + 6], i7 = einv[p + 7];
        float a0 = b2f(xW16[(v0 << 5) + c]);
        float a1 = b2f(xW16[(v1 << 5) + c]);
        float a2 = b2f(xW16[(v2 << 5) + c]);
        float a3 = b2f(xW16[(v3 << 5) + c]);
        float a4 = b2f(xW16[(v4 << 5) + c]);
        float a5 = b2f(xW16[(v5 << 5) + c]);
        float a6 = b2f(xW16[(v6 << 5) + c]);
        float a7 = b2f(xW16[(v7 << 5) + c]);
        acc0 = fmaf(a0, i0, acc0);
        acc1 = fmaf(a1, i1, acc1);
        acc0 = fmaf(a2, i2, acc0);
        acc1 = fmaf(a3, i3, acc1);
        acc0 = fmaf(a4, i4, acc0);
        acc1 = fmaf(a5, i5, acc1);
        acc0 = fmaf(a6, i6, acc0);
        acc1 = fmaf(a7, i7, acc1);
    }
    for (; p + 3 < p1; p += 4) {
        int v0 = csr[p], v1 = csr[p + 1], v2 = csr[p + 2], v3 = csr[p + 3];
        float i0 = einv[p], i1 = einv[p + 1], i2 = einv[p + 2], i3 = einv[p + 3];
        acc0 = fmaf(b2f(xW16[(v0 << 5) + c]), i0, acc0);
        acc1 = fmaf(b2f(xW16[(v1 << 5) + c]), i1, acc1);
        acc0 = fmaf(b2f(xW16[(v2 << 5) + c]), i2, acc0);
        acc1 = fmaf(b2f(xW16[(v3 << 5) + c]), i3, acc1);
    }
    if (p + 1 < p1) {
        int v0 = csr[p], v1 = csr[p + 1];
        acc0 = fmaf(b2f(xW16[(v0 << 5) + c]), einv[p], acc0);
        acc1 = fmaf(b2f(xW16[(v1 << 5) + c]), einv[p + 1], acc1);
        p += 2;
    }
    if (p < p1)
        acc0 = fmaf(b2f(xW16[(csr[p] << 5) + c]), einv[p], acc0);

    // root term + bias + relu
    const float* wr = root1 + c;
    float acc = acc0 + acc1 + b1[c];
    acc += xv0.x * wr[0]   + xv0.y * wr[32]  + xv0.z * wr[64]  + xv0.w * wr[96];
    acc += xv1.x * wr[128] + xv1.y * wr[160] + xv1.z * wr[192] + xv1.w * wr[224];
    acc += xv2.x * wr[256] + xv2.y * wr[288] + xv2.z * wr[320] + xv2.w * wr[352];
    acc += xv3.x * wr[384] + xv3.y * wr[416] + xv3.z * wr[448] + xv3.w * wr[480];
    float hval = fmaxf(acc, 0.0f);

    EPILOGUE_V2(sw2, hval, node, c, hW16, hroot, b2)
}

// ---------------------------------------------------------------------------
// l1 fallback (no room for xW16): half-wave per node, direct per-edge dot.
// ---------------------------------------------------------------------------
__global__ __launch_bounds__(256) void l1_fb_kernel(const float* __restrict__ x,
                                                    const int* __restrict__ csr,
                                                    const float* __restrict__ einv,
                                                    const int* __restrict__ rowptr,
                                                    const float* __restrict__ W1,
                                                    const float* __restrict__ root1,
                                                    const float* __restrict__ b1,
                                                    const float* __restrict__ W2,
                                                    const float* __restrict__ root2,
                                                    const float* __restrict__ b2,
                                                    unsigned int* __restrict__ hW16,
                                                    float* __restrict__ hroot, int N) {
    __shared__ float sW[N_REL * IN_CH * HID_CH];   // 16 KB
    __shared__ float2 sw2[32 * 9];
    for (int i = threadIdx.x; i < N_REL * IN_CH * HID_CH; i += 256) sW[i] = W1[i];
    STAGE_SW2(sw2, W2, root2)
    __syncthreads();

    int gid  = blockIdx.x * 256 + threadIdx.x;
    int node = gid >> 5;
    int c    = gid & 31;
    if (node >= N) return;

    int p0 = __ldg(&rowptr[node]);
    int p1 = __ldg(&rowptr[node + 1]);

    float acc = 0.0f;
    for (int p = p0; p < p1; ++p) {
        int v = csr[p];
        int s = v >> 3, r = v & 7;
        const float4* xsv = (const float4*)(x + ((long)s << 4));
        float4 q0 = xsv[0], q1 = xsv[1], q2 = xsv[2], q3 = xsv[3];
        const float* w = sW + ((r * IN_CH) * HID_CH) + c;
        float a;
        a  = q0.x * w[0]   + q0.y * w[32]  + q0.z * w[64]  + q0.w * w[96];
        a += q1.x * w[128] + q1.y * w[160] + q1.z * w[192] + q1.w * w[224];
        a += q2.x * w[256] + q2.y * w[288] + q2.z * w[320] + q2.w * w[352];
        a += q3.x * w[384] + q3.y * w[416] + q3.z * w[448] + q3.w * w[480];
        acc = fmaf(a, einv[p], acc);
    }

    const float4* xs = (const float4*)(x + ((long)node << 4));
    float4 v0 = xs[0], v1 = xs[1], v2 = xs[2], v3 = xs[3];
    const float* wr = root1 + c;
    acc += b1[c];
    acc += v0.x * wr[0]   + v0.y * wr[32]  + v0.z * wr[64]  + v0.w * wr[96];
    acc += v1.x * wr[128] + v1.y * wr[160] + v1.z * wr[192] + v1.w * wr[224];
    acc += v2.x * wr[256] + v2.y * wr[288] + v2.z * wr[320] + v2.w * wr[352];
    acc += v3.x * wr[384] + v3.y * wr[416] + v3.z * wr[448] + v3.w * wr[480];
    float hval = fmaxf(acc, 0.0f);

    EPILOGUE_V2(sw2, hval, node, c, hW16, hroot, b2)
}

// ---------------------------------------------------------------------------
// l2 flat: 16 lanes per node, flat edge loop; hW16 gather index == csr word.
// ---------------------------------------------------------------------------
__global__ __launch_bounds__(256) void l2_flat_kernel(const int* __restrict__ csr,
                                                      const float* __restrict__ einv,
                                                      const int* __restrict__ rowptr,
                                                      const unsigned int* __restrict__ hW16,
                                                      const float* __restrict__ hroot,
                                                      float* __restrict__ out, int N) {
    int gid  = blockIdx.x * 256 + threadIdx.x;
    int node = gid >> 4;
    int l    = gid & 15;
    if (node >= N) return;

    int p0 = __ldg(&rowptr[node]);
    int p1 = __ldg(&rowptr[node + 1]);

    float o0 = 0.0f, o1 = 0.0f;
    for (int p = p0 + l; p < p1; p += 16) {
        int v = csr[p];
        float w = einv[p];
        unsigned u = hW16[v];
        o0 = fmaf(b2f((unsigned short)u), w, o0);
        o1 = fmaf(b2f((unsigned short)(u >> 16)), w, o1);
    }

#pragma unroll
    for (int m = 1; m < 16; m <<= 1) {
        o0 += __shfl_xor(o0, m, 64);
        o1 += __shfl_xor(o1, m, 64);
    }

    if (l == 0) {
        float2 rt = *(const float2*)(hroot + ((long)node << 1));   // includes b2
        o0 += rt.x; o1 += rt.y;
        float mx = fmaxf(o0, o1);
        float lg = mx + logf(__expf(o0 - mx) + __expf(o1 - mx));
        *(float2*)(out + ((long)node << 1)) = make_float2(o0 - lg, o1 - lg);
    }
}

// ---------------------------------------------------------------------------
extern "C" void kernel_launch(void* const* d_in, const int* in_sizes, int n_in,
                              void* d_out, int out_size, void* d_ws, size_t ws_size,
                              hipStream_t stream) {
    const float* x     = (const float*)d_in[0];
    const int*   eidx  = (const int*)d_in[1];
    const int*   etype = (const int*)d_in[2];
    const float* W1    = (const float*)d_in[3];
    const float* root1 = (const float*)d_in[4];
    const float* b1    = (const float*)d_in[5];
    const float* W2    = (const float*)d_in[6];
    const float* root2 = (const float*)d_in[7];
    const float* b2    = (const float*)d_in[8];
    float* out = (float*)d_out;

    const int N = in_sizes[0] / IN_CH;
    const int E = in_sizes[2];
    const int nbins   = (N + BIN_NODES - 1) >> BIN_BITS;
    const int chunksz = (E + NCHUNK - 1) / NCHUNK;
    const int M2      = nbins * NCHUNK;
    const int* src = eidx;
    const int* dst = eidx + E;

    char* wp = (char*)d_ws;
    auto take = [&](size_t bytes) {
        char* p = wp;
        wp += (bytes + 63) & ~(size_t)63;
        return p;
    };
    int*   H        = (int*)take((size_t)M2 * sizeof(int));
    int*   binstart = (int*)take(512 * sizeof(int));
    int*   rowptr   = (int*)take((size_t)(nbins * BIN_NODES + 1) * sizeof(int));
    int*   csr      = (int*)take((size_t)E * sizeof(int));
    float* einv     = (float*)take((size_t)E * sizeof(float));
    int*   be       = (int*)take((size_t)E * sizeof(int));
    unsigned int* hW16 = (unsigned int*)take((size_t)N * N_REL * sizeof(unsigned int));
    float* hroot    = (float*)take((size_t)N * 2 * sizeof(float));
    unsigned short* xW16 = (unsigned short*)take((size_t)N * N_REL * HID_CH * sizeof(unsigned short));
    bool use_xw = ((size_t)(wp - (char*)d_ws) <= ws_size);

    const int B = 256;
    const int nxw = use_xw ? (N + XW_TILE - 1) / XW_TILE : 0;

    prep_kernel<<<nxw + NCHUNK, B, 0, stream>>>(x, W1, xW16, dst, H, N, E, nbins, chunksz, nxw);
    part_scatter_kernel<<<NCHUNK, B, 0, stream>>>(src, dst, etype, H, binstart, be, E, nbins, chunksz);
    bin_build_kernel<<<nbins, B, 0, stream>>>(be, binstart, rowptr, csr, einv, E, nbins);

    if (use_xw) {
        l1_fused_kernel<<<(N * 32 + B - 1) / B, B, 0, stream>>>(
            x, csr, einv, rowptr, xW16, root1, b1, W2, root2, b2, hW16, hroot, N);
    } else {
        l1_fb_kernel<<<(N * 32 + B - 1) / B, B, 0, stream>>>(
            x, csr, einv, rowptr, W1, root1, b1, W2, root2, b2, hW16, hroot, N);
    }

    l2_flat_kernel<<<(N * 16 + B - 1) / B, B, 0, stream>>>(csr, einv, rowptr, hW16, hroot, out, N);
}